// Round 1
// baseline (150.293 us; speedup 1.0000x reference)
//
#include <hip/hip_runtime.h>
#include <hip/hip_bf16.h>
#include <stdint.h>

typedef __attribute__((ext_vector_type(8))) short short8;
typedef __attribute__((ext_vector_type(4))) float f32x4;

#define N_PTS 8192
#define M_PTS 8192
#define DIM   512
#define KDIM  128

// ---- float <-> order-preserving uint key (for atomicMin on float) ----
__device__ __forceinline__ unsigned fenc(float f) {
  unsigned u = __float_as_uint(f);
  return (u & 0x80000000u) ? ~u : (u | 0x80000000u);
}
__device__ __forceinline__ float fdec(unsigned k) {
  unsigned u = (k & 0x80000000u) ? (k ^ 0x80000000u) : ~k;
  return __uint_as_float(u);
}

// ---- async global -> LDS, 16B per lane ----
__device__ __forceinline__ void async_copy16(const void* g, void* l) {
  __builtin_amdgcn_global_load_lds(
      (const __attribute__((address_space(1))) void*)g,
      (__attribute__((address_space(3))) void*)l, 16, 0, 0);
}

// =====================================================================
// Kernel 1: per 8 rows of x: bf16 cast, x_sq, phi_b = logsumexp(x@W)
// grid = N/8 blocks, 128 threads
// =====================================================================
__global__ __launch_bounds__(128)
void prep_x_kernel(const float* __restrict__ x, const float* __restrict__ W,
                   __hip_bfloat16* __restrict__ Xb, float* __restrict__ phi_b,
                   float* __restrict__ xsq) {
  __shared__ float xs[8][DIM];
  __shared__ float lg[8][KDIM];
  const int t = threadIdx.x;
  const int n0 = blockIdx.x * 8;

  const float4* xv = (const float4*)(x + (size_t)n0 * DIM);
#pragma unroll
  for (int i = 0; i < 8; ++i) {
    float4 v = xv[i * 128 + t];
    xs[i][t * 4 + 0] = v.x;
    xs[i][t * 4 + 1] = v.y;
    xs[i][t * 4 + 2] = v.z;
    xs[i][t * 4 + 3] = v.w;
    __hip_bfloat16* o = Xb + (size_t)(n0 + i) * DIM + t * 4;
    o[0] = __float2bfloat16(v.x);
    o[1] = __float2bfloat16(v.y);
    o[2] = __float2bfloat16(v.z);
    o[3] = __float2bfloat16(v.w);
  }
  __syncthreads();

  // logits: thread t owns logit column t (coalesced W reads)
  float acc[8] = {0.f, 0.f, 0.f, 0.f, 0.f, 0.f, 0.f, 0.f};
  for (int d = 0; d < DIM; ++d) {
    float wv = W[d * KDIM + t];
#pragma unroll
    for (int r = 0; r < 8; ++r) acc[r] += xs[r][d] * wv;
  }
#pragma unroll
  for (int r = 0; r < 8; ++r) lg[r][t] = acc[r];
  __syncthreads();

  // per-row logsumexp + sumsq: 16 threads per row
  const int r = t >> 4, j = t & 15;
  float mx = -3.4e38f;
#pragma unroll
  for (int i = 0; i < 8; ++i) mx = fmaxf(mx, lg[r][j + 16 * i]);
#pragma unroll
  for (int m = 1; m <= 8; m <<= 1) mx = fmaxf(mx, __shfl_xor(mx, m));
  float s = 0.f;
#pragma unroll
  for (int i = 0; i < 8; ++i) s += __expf(lg[r][j + 16 * i] - mx);
  float sq = 0.f;
#pragma unroll
  for (int i = 0; i < 32; ++i) {
    float v = xs[r][j + 16 * i];
    sq += v * v;
  }
#pragma unroll
  for (int m = 1; m <= 8; m <<= 1) {
    s += __shfl_xor(s, m);
    sq += __shfl_xor(sq, m);
  }
  if (j == 0) {
    phi_b[n0 + r] = mx + logf(s);
    xsq[n0 + r] = sq;
  }
}

// =====================================================================
// Kernel 2: per row of target: bf16 cast + t_sq.  grid = M, 128 threads
// =====================================================================
__global__ __launch_bounds__(128)
void prep_t_kernel(const float* __restrict__ tgt, __hip_bfloat16* __restrict__ Tb,
                   float* __restrict__ tsq) {
  const int row = blockIdx.x;
  const int t = threadIdx.x;
  float4 v = ((const float4*)(tgt + (size_t)row * DIM))[t];
  float sq = v.x * v.x + v.y * v.y + v.z * v.z + v.w * v.w;
  __hip_bfloat16* o = Tb + (size_t)row * DIM + t * 4;
  o[0] = __float2bfloat16(v.x);
  o[1] = __float2bfloat16(v.y);
  o[2] = __float2bfloat16(v.z);
  o[3] = __float2bfloat16(v.w);
#pragma unroll
  for (int m = 1; m <= 32; m <<= 1) sq += __shfl_xor(sq, m);
  __shared__ float partial[2];
  if ((t & 63) == 0) partial[t >> 6] = sq;
  __syncthreads();
  if (t == 0) tsq[row] = partial[0] + partial[1];
}

// =====================================================================
// Kernel 3: init keys to +inf (0xFFFFFFFF)
// =====================================================================
__global__ void init_keys_kernel(unsigned* __restrict__ keys, int m) {
  int i = blockIdx.x * blockDim.x + threadIdx.x;
  if (i < m) keys[i] = 0xFFFFFFFFu;
}

// =====================================================================
// Kernel 4: fused bf16 MFMA GEMM (x @ target^T) + min_n(phi_b[n]-dot)
// 128x128 tile, BK=32, 4 waves (2x2), 16x16x32 MFMA
// grid = (M/128, N/128), 256 threads
// =====================================================================
#define BT 128
#define BKS 32

__global__ __launch_bounds__(256)
void gemm_min_kernel(const short* __restrict__ Xb, const short* __restrict__ Tb,
                     const float* __restrict__ phi_b, unsigned* __restrict__ keys) {
  __shared__ __align__(16) short As[BT * BKS];  // [row(n)][k] 128x32
  __shared__ __align__(16) short Bs[BT * BKS];  // [row(m)][k]

  const int tid = threadIdx.x;
  const int wave = tid >> 6, lane = tid & 63;
  const int n0 = blockIdx.y * BT;
  const int m0 = blockIdx.x * BT;

  // staging coords: 256 threads x 16B = 64 rows per issue, 2 issues per tile
  const int srow = tid >> 2;          // 0..63
  const int sk8 = (tid & 3) * 8;      // element offset in 32-k slice

  const int wr = wave >> 1, wc = wave & 1;
  const int fr = lane & 15;           // frag row/col within 16
  const int kq = (lane >> 4) * 8;     // k-slice of this lane group

  f32x4 acc[4][4] = {};

  for (int kt = 0; kt < DIM / BKS; ++kt) {
    const int k0 = kt * BKS;
    // stage A (x rows) and B (target rows), rows 0-63 then 64-127
    async_copy16(Xb + (size_t)(n0 + srow) * DIM + k0 + sk8, &As[wave * 512]);
    async_copy16(Xb + (size_t)(n0 + srow + 64) * DIM + k0 + sk8, &As[2048 + wave * 512]);
    async_copy16(Tb + (size_t)(m0 + srow) * DIM + k0 + sk8, &Bs[wave * 512]);
    async_copy16(Tb + (size_t)(m0 + srow + 64) * DIM + k0 + sk8, &Bs[2048 + wave * 512]);
    __syncthreads();

    short8 a[4], b[4];
#pragma unroll
    for (int i = 0; i < 4; ++i)
      a[i] = *(const short8*)&As[(wr * 64 + i * 16 + fr) * BKS + kq];
#pragma unroll
    for (int j = 0; j < 4; ++j)
      b[j] = *(const short8*)&Bs[(wc * 64 + j * 16 + fr) * BKS + kq];
#pragma unroll
    for (int i = 0; i < 4; ++i)
#pragma unroll
      for (int j = 0; j < 4; ++j)
        acc[i][j] = __builtin_amdgcn_mfma_f32_16x16x32_bf16(a[i], b[j], acc[i][j], 0, 0, 0);
    __syncthreads();
  }

  // Epilogue: v = phi_b[n] - dot(n,m); per-column min over the 128 n's.
  // C/D layout: col = lane&15, row = (lane>>4)*4 + q  (m89-verified)
  const int rq = (lane >> 4) * 4;
  float mv[4] = {3.4e38f, 3.4e38f, 3.4e38f, 3.4e38f};
#pragma unroll
  for (int i = 0; i < 4; ++i) {
    float pb[4];
#pragma unroll
    for (int q = 0; q < 4; ++q) pb[q] = phi_b[n0 + wr * 64 + i * 16 + rq + q];
#pragma unroll
    for (int j = 0; j < 4; ++j)
#pragma unroll
      for (int q = 0; q < 4; ++q) mv[j] = fminf(mv[j], pb[q] - acc[i][j][q]);
  }
#pragma unroll
  for (int j = 0; j < 4; ++j) {
    float v = mv[j];
    v = fminf(v, __shfl_xor(v, 16));
    v = fminf(v, __shfl_xor(v, 32));
    if ((lane >> 4) == 0) {
      atomicMin(&keys[m0 + wc * 64 + j * 16 + fr], fenc(v));
    }
  }
}

// =====================================================================
// Kernel 5: final reduce: mean(phi_k) + mean(phi_c). 1 block.
// =====================================================================
__global__ __launch_bounds__(256)
void finalize_kernel(const float* __restrict__ xsq, const float* __restrict__ phi_b,
                     const float* __restrict__ tsq, const unsigned* __restrict__ keys,
                     float* __restrict__ out) {
  const int t = threadIdx.x;
  double sk = 0.0, sc = 0.0;
  for (int n = t; n < N_PTS; n += 256) sk += 0.5 * (double)xsq[n] - (double)phi_b[n];
  for (int m = t; m < M_PTS; m += 256) sc += 0.5 * (double)tsq[m] + (double)fdec(keys[m]);
  const int lane = t & 63, wv = t >> 6;
#pragma unroll
  for (int m = 1; m <= 32; m <<= 1) {
    sk += __shfl_xor(sk, m);
    sc += __shfl_xor(sc, m);
  }
  __shared__ double pk[4], pc[4];
  if (lane == 0) { pk[wv] = sk; pc[wv] = sc; }
  __syncthreads();
  if (t == 0) {
    double a = pk[0] + pk[1] + pk[2] + pk[3];
    double c = pc[0] + pc[1] + pc[2] + pc[3];
    out[0] = (float)(a / N_PTS + c / M_PTS);
  }
}

// =====================================================================
extern "C" void kernel_launch(void* const* d_in, const int* in_sizes, int n_in,
                              void* d_out, int out_size, void* d_ws, size_t ws_size,
                              hipStream_t stream) {
  const float* x = (const float*)d_in[0];
  const float* tgt = (const float*)d_in[1];
  const float* W = (const float*)d_in[2];

  char* ws = (char*)d_ws;
  const size_t XB_BYTES = (size_t)N_PTS * DIM * 2;
  const size_t TB_BYTES = (size_t)M_PTS * DIM * 2;
  __hip_bfloat16* Xb = (__hip_bfloat16*)ws;
  __hip_bfloat16* Tb = (__hip_bfloat16*)(ws + XB_BYTES);
  float* phi_b = (float*)(ws + XB_BYTES + TB_BYTES);
  float* xsq = phi_b + N_PTS;
  float* tsq = xsq + N_PTS;
  unsigned* keys = (unsigned*)(tsq + M_PTS);

  prep_x_kernel<<<N_PTS / 8, 128, 0, stream>>>(x, W, Xb, phi_b, xsq);
  prep_t_kernel<<<M_PTS, 128, 0, stream>>>(tgt, Tb, tsq);
  init_keys_kernel<<<(M_PTS + 255) / 256, 256, 0, stream>>>(keys, M_PTS);
  gemm_min_kernel<<<dim3(M_PTS / BT, N_PTS / BT), 256, 0, stream>>>(
      (const short*)Xb, (const short*)Tb, phi_b, keys);
  finalize_kernel<<<1, 256, 0, stream>>>(xsq, phi_b, tsq, keys, (float*)d_out);
}

// Round 2
// 124.789 us; speedup vs baseline: 1.2044x; 1.2044x over previous
//
#include <hip/hip_runtime.h>
#include <hip/hip_bf16.h>
#include <stdint.h>

typedef __attribute__((ext_vector_type(8))) short short8;
typedef __attribute__((ext_vector_type(4))) float f32x4;

#define N_PTS 8192
#define M_PTS 8192
#define DIM   512
#define KDIM  128
#define BT    128
#define BKS   32

// ---- float <-> order-preserving uint key (for atomicMin on float) ----
__device__ __forceinline__ unsigned fenc(float f) {
  unsigned u = __float_as_uint(f);
  return (u & 0x80000000u) ? ~u : (u | 0x80000000u);
}
__device__ __forceinline__ float fdec(unsigned k) {
  unsigned u = (k & 0x80000000u) ? (k ^ 0x80000000u) : ~k;
  return __uint_as_float(u);
}

__device__ __forceinline__ unsigned short f2bf(float f) {
  union { __hip_bfloat16 h; unsigned short u; } c;
  c.h = __float2bfloat16(f);
  return c.u;
}

// ---- async global -> LDS, 16B per lane ----
__device__ __forceinline__ void async_copy16(const void* g, void* l) {
  __builtin_amdgcn_global_load_lds(
      (const __attribute__((address_space(1))) void*)g,
      (__attribute__((address_space(3))) void*)l, 16, 0, 0);
}

// ---- LDS slot swizzle: 4 slots of 16B per 64B row; 2-way (free) banks ----
__device__ __forceinline__ int swz_slot(int row, int slot) {
  return slot ^ ((row >> 1) & 3);
}

// =====================================================================
// Kernel 1: streaming cast x & target -> bf16, row sumsq, key init.
// One 64-lane wave per row. grid = (N+M)/4 blocks of 256.
// =====================================================================
__global__ __launch_bounds__(256)
void cast_rows_kernel(const float* __restrict__ x, const float* __restrict__ tgt,
                      unsigned short* __restrict__ Xb, unsigned short* __restrict__ Tb,
                      float* __restrict__ xsq, float* __restrict__ tsq,
                      unsigned* __restrict__ keys) {
  const int gw = (blockIdx.x * 256 + threadIdx.x) >> 6;
  const int lane = threadIdx.x & 63;
  const float* src;
  unsigned short* dst;
  float* sq;
  int trow = -1;
  if (gw < N_PTS) {
    src = x + (size_t)gw * DIM;
    dst = Xb + (size_t)gw * DIM;
    sq = xsq + gw;
  } else {
    trow = gw - N_PTS;
    src = tgt + (size_t)trow * DIM;
    dst = Tb + (size_t)trow * DIM;
    sq = tsq + trow;
  }
  float s = 0.f;
#pragma unroll
  for (int i = 0; i < 2; ++i) {
    float4 v = ((const float4*)src)[i * 64 + lane];
    s += v.x * v.x + v.y * v.y + v.z * v.z + v.w * v.w;
    ushort4 o;
    o.x = f2bf(v.x); o.y = f2bf(v.y); o.z = f2bf(v.z); o.w = f2bf(v.w);
    ((ushort4*)dst)[i * 64 + lane] = o;
  }
#pragma unroll
  for (int m = 1; m <= 32; m <<= 1) s += __shfl_xor(s, m);
  if (lane == 0) {
    *sq = s;
    if (trow >= 0) keys[trow] = 0xFFFFFFFFu;
  }
}

// =====================================================================
// Kernel 2: W [D][K] fp32 -> WbT [K][D] bf16 (transposed cast)
// =====================================================================
__global__ __launch_bounds__(256)
void prep_w_kernel(const float* __restrict__ W, unsigned short* __restrict__ WbT) {
  const int o = blockIdx.x * 256 + threadIdx.x;  // 0..65535
  const int k = o >> 9, d = o & 511;
  WbT[o] = f2bf(W[d * KDIM + k]);
}

// =====================================================================
// Kernel 3: phi_b = logsumexp(Xb @ WbT^T) via MFMA + in-LDS logsumexp.
// Tile 128 n x 128 k (full logit width). grid = N/128 = 64 blocks.
// =====================================================================
__global__ __launch_bounds__(256)
void phi_b_kernel(const short* __restrict__ Xb, const short* __restrict__ WbT,
                  float* __restrict__ phi_b) {
  __shared__ __align__(16) short As[BT * BKS];
  __shared__ __align__(16) short Bs[BT * BKS];
  __shared__ __align__(16) float lg[128][136];

  const int tid = threadIdx.x;
  const int wave = tid >> 6, lane = tid & 63;
  const int n0 = blockIdx.x * BT;
  const int srow = tid >> 2;
  const int sk8 = swz_slot(srow, tid & 3) * 8;
  const int wr = wave >> 1, wc = wave & 1;
  const int fr = lane & 15, g = lane >> 4;

  f32x4 acc[4][4] = {};
  for (int kt = 0; kt < DIM / BKS; ++kt) {
    const int k0 = kt * BKS;
    async_copy16(Xb + (size_t)(n0 + srow) * DIM + k0 + sk8, &As[wave * 512]);
    async_copy16(Xb + (size_t)(n0 + srow + 64) * DIM + k0 + sk8, &As[2048 + wave * 512]);
    async_copy16(WbT + (size_t)srow * DIM + k0 + sk8, &Bs[wave * 512]);
    async_copy16(WbT + (size_t)(srow + 64) * DIM + k0 + sk8, &Bs[2048 + wave * 512]);
    __syncthreads();
    short8 a[4], b[4];
#pragma unroll
    for (int i = 0; i < 4; ++i) {
      const int R = wr * 64 + i * 16 + fr;
      a[i] = *(const short8*)&As[R * BKS + swz_slot(R, g) * 8];
    }
#pragma unroll
    for (int j = 0; j < 4; ++j) {
      const int R = wc * 64 + j * 16 + fr;
      b[j] = *(const short8*)&Bs[R * BKS + swz_slot(R, g) * 8];
    }
#pragma unroll
    for (int i = 0; i < 4; ++i)
#pragma unroll
      for (int j = 0; j < 4; ++j)
        acc[i][j] = __builtin_amdgcn_mfma_f32_16x16x32_bf16(a[i], b[j], acc[i][j], 0, 0, 0);
    __syncthreads();
  }

  // scatter logits into LDS: row n, col k  (C layout: col=lane&15, row=(lane>>4)*4+q)
  const int rq = g * 4;
#pragma unroll
  for (int i = 0; i < 4; ++i)
#pragma unroll
    for (int j = 0; j < 4; ++j)
#pragma unroll
      for (int q = 0; q < 4; ++q)
        lg[wr * 64 + i * 16 + rq + q][wc * 64 + j * 16 + fr] = acc[i][j][q];
  __syncthreads();

  // per-row logsumexp: 2 threads per row, 64 cols each
  const int row = tid >> 1, half = tid & 1;
  const float4* lr = (const float4*)(&lg[row][half * 64]);
  float mx = -3.4e38f;
#pragma unroll
  for (int c = 0; c < 16; ++c) {
    float4 v = lr[c];
    mx = fmaxf(mx, fmaxf(fmaxf(v.x, v.y), fmaxf(v.z, v.w)));
  }
  mx = fmaxf(mx, __shfl_xor(mx, 1));
  float s = 0.f;
#pragma unroll
  for (int c = 0; c < 16; ++c) {
    float4 v = lr[c];
    s += __expf(v.x - mx) + __expf(v.y - mx) + __expf(v.z - mx) + __expf(v.w - mx);
  }
  s += __shfl_xor(s, 1);
  if (half == 0) phi_b[n0 + row] = mx + logf(s);
}

// =====================================================================
// Kernel 4: fused bf16 MFMA GEMM (x @ target^T) + min_n(phi_b[n]-dot)
// 128x128 tile, BK=32, 4 waves (2x2), swizzled LDS. grid = (M/128, N/128)
// =====================================================================
__global__ __launch_bounds__(256)
void gemm_min_kernel(const short* __restrict__ Xb, const short* __restrict__ Tb,
                     const float* __restrict__ phi_b, unsigned* __restrict__ keys) {
  __shared__ __align__(16) short As[BT * BKS];
  __shared__ __align__(16) short Bs[BT * BKS];

  const int tid = threadIdx.x;
  const int wave = tid >> 6, lane = tid & 63;
  const int n0 = blockIdx.y * BT;
  const int m0 = blockIdx.x * BT;

  const int srow = tid >> 2;
  const int sk8 = swz_slot(srow, tid & 3) * 8;  // pre-swizzled global source

  const int wr = wave >> 1, wc = wave & 1;
  const int fr = lane & 15, g = lane >> 4;

  f32x4 acc[4][4] = {};

  for (int kt = 0; kt < DIM / BKS; ++kt) {
    const int k0 = kt * BKS;
    async_copy16(Xb + (size_t)(n0 + srow) * DIM + k0 + sk8, &As[wave * 512]);
    async_copy16(Xb + (size_t)(n0 + srow + 64) * DIM + k0 + sk8, &As[2048 + wave * 512]);
    async_copy16(Tb + (size_t)(m0 + srow) * DIM + k0 + sk8, &Bs[wave * 512]);
    async_copy16(Tb + (size_t)(m0 + srow + 64) * DIM + k0 + sk8, &Bs[2048 + wave * 512]);
    __syncthreads();

    short8 a[4], b[4];
#pragma unroll
    for (int i = 0; i < 4; ++i) {
      const int R = wr * 64 + i * 16 + fr;
      a[i] = *(const short8*)&As[R * BKS + swz_slot(R, g) * 8];
    }
#pragma unroll
    for (int j = 0; j < 4; ++j) {
      const int R = wc * 64 + j * 16 + fr;
      b[j] = *(const short8*)&Bs[R * BKS + swz_slot(R, g) * 8];
    }
#pragma unroll
    for (int i = 0; i < 4; ++i)
#pragma unroll
      for (int j = 0; j < 4; ++j)
        acc[i][j] = __builtin_amdgcn_mfma_f32_16x16x32_bf16(a[i], b[j], acc[i][j], 0, 0, 0);
    __syncthreads();
  }

  // Epilogue: v = phi_b[n] - dot(n,m); per-column min over the 128 n's.
  const int rq = g * 4;
  float mv[4] = {3.4e38f, 3.4e38f, 3.4e38f, 3.4e38f};
#pragma unroll
  for (int i = 0; i < 4; ++i) {
    float pb[4];
#pragma unroll
    for (int q = 0; q < 4; ++q) pb[q] = phi_b[n0 + wr * 64 + i * 16 + rq + q];
#pragma unroll
    for (int j = 0; j < 4; ++j)
#pragma unroll
      for (int q = 0; q < 4; ++q) mv[j] = fminf(mv[j], pb[q] - acc[i][j][q]);
  }
#pragma unroll
  for (int j = 0; j < 4; ++j) {
    float v = mv[j];
    v = fminf(v, __shfl_xor(v, 16));
    v = fminf(v, __shfl_xor(v, 32));
    if (g == 0) {
      atomicMin(&keys[m0 + wc * 64 + j * 16 + fr], fenc(v));
    }
  }
}

// =====================================================================
// Kernel 5: final reduce: mean(phi_k) + mean(phi_c). 1 block.
// =====================================================================
__global__ __launch_bounds__(256)
void finalize_kernel(const float* __restrict__ xsq, const float* __restrict__ phi_b,
                     const float* __restrict__ tsq, const unsigned* __restrict__ keys,
                     float* __restrict__ out) {
  const int t = threadIdx.x;
  double sk = 0.0, sc = 0.0;
  for (int n = t; n < N_PTS; n += 256) sk += 0.5 * (double)xsq[n] - (double)phi_b[n];
  for (int m = t; m < M_PTS; m += 256) sc += 0.5 * (double)tsq[m] + (double)fdec(keys[m]);
  const int lane = t & 63, wv = t >> 6;
#pragma unroll
  for (int m = 1; m <= 32; m <<= 1) {
    sk += __shfl_xor(sk, m);
    sc += __shfl_xor(sc, m);
  }
  __shared__ double pk[4], pc[4];
  if (lane == 0) { pk[wv] = sk; pc[wv] = sc; }
  __syncthreads();
  if (t == 0) {
    double a = pk[0] + pk[1] + pk[2] + pk[3];
    double c = pc[0] + pc[1] + pc[2] + pc[3];
    out[0] = (float)(a / N_PTS + c / M_PTS);
  }
}

// =====================================================================
extern "C" void kernel_launch(void* const* d_in, const int* in_sizes, int n_in,
                              void* d_out, int out_size, void* d_ws, size_t ws_size,
                              hipStream_t stream) {
  const float* x = (const float*)d_in[0];
  const float* tgt = (const float*)d_in[1];
  const float* W = (const float*)d_in[2];

  char* ws = (char*)d_ws;
  const size_t XB_BYTES = (size_t)N_PTS * DIM * 2;
  const size_t TB_BYTES = (size_t)M_PTS * DIM * 2;
  const size_t WT_BYTES = (size_t)KDIM * DIM * 2;
  unsigned short* Xb = (unsigned short*)ws;
  unsigned short* Tb = (unsigned short*)(ws + XB_BYTES);
  unsigned short* WbT = (unsigned short*)(ws + XB_BYTES + TB_BYTES);
  float* phi_b = (float*)(ws + XB_BYTES + TB_BYTES + WT_BYTES);
  float* xsq = phi_b + N_PTS;
  float* tsq = xsq + N_PTS;
  unsigned* keys = (unsigned*)(tsq + M_PTS);

  cast_rows_kernel<<<(N_PTS + M_PTS) / 4, 256, 0, stream>>>(x, tgt, Xb, Tb, xsq, tsq, keys);
  prep_w_kernel<<<(KDIM * DIM) / 256, 256, 0, stream>>>(W, WbT);
  phi_b_kernel<<<N_PTS / BT, 256, 0, stream>>>((const short*)Xb, (const short*)WbT, phi_b);
  gemm_min_kernel<<<dim3(M_PTS / BT, N_PTS / BT), 256, 0, stream>>>(
      (const short*)Xb, (const short*)Tb, phi_b, keys);
  finalize_kernel<<<1, 256, 0, stream>>>(xsq, phi_b, tsq, keys, (float*)d_out);
}

// Round 3
// 107.077 us; speedup vs baseline: 1.4036x; 1.1654x over previous
//
#include <hip/hip_runtime.h>
#include <hip/hip_bf16.h>
#include <stdint.h>

typedef __attribute__((ext_vector_type(8))) short short8;
typedef __attribute__((ext_vector_type(4))) float f32x4;

#define N_PTS 8192
#define M_PTS 8192
#define DIM   512
#define KDIM  128
#define BT    128   // phi_b tile
#define BKS   32
#define BM    256   // gemm tile
#define BN    256
#define BKQ   32

// ---- float <-> order-preserving uint key (for atomicMin on float) ----
__device__ __forceinline__ unsigned fenc(float f) {
  unsigned u = __float_as_uint(f);
  return (u & 0x80000000u) ? ~u : (u | 0x80000000u);
}
__device__ __forceinline__ float fdec(unsigned k) {
  unsigned u = (k & 0x80000000u) ? (k ^ 0x80000000u) : ~k;
  return __uint_as_float(u);
}

__device__ __forceinline__ unsigned short f2bf(float f) {
  union { __hip_bfloat16 h; unsigned short u; } c;
  c.h = __float2bfloat16(f);
  return c.u;
}

// ---- async global -> LDS, 16B per lane ----
__device__ __forceinline__ void async_copy16(const void* g, void* l) {
  __builtin_amdgcn_global_load_lds(
      (const __attribute__((address_space(1))) void*)g,
      (__attribute__((address_space(3))) void*)l, 16, 0, 0);
}

// ---- LDS slot swizzle (verified: conflicts -> 0): 4 slots of 16B/row ----
__device__ __forceinline__ int swz_slot(int row, int slot) {
  return slot ^ ((row >> 1) & 3);
}

// =====================================================================
// Kernel 1: streaming cast x & target -> bf16, row sumsq, key init.
// =====================================================================
__global__ __launch_bounds__(256)
void cast_rows_kernel(const float* __restrict__ x, const float* __restrict__ tgt,
                      unsigned short* __restrict__ Xb, unsigned short* __restrict__ Tb,
                      float* __restrict__ xsq, float* __restrict__ tsq,
                      unsigned* __restrict__ keys) {
  const int gw = (blockIdx.x * 256 + threadIdx.x) >> 6;
  const int lane = threadIdx.x & 63;
  const float* src;
  unsigned short* dst;
  float* sq;
  int trow = -1;
  if (gw < N_PTS) {
    src = x + (size_t)gw * DIM;
    dst = Xb + (size_t)gw * DIM;
    sq = xsq + gw;
  } else {
    trow = gw - N_PTS;
    src = tgt + (size_t)trow * DIM;
    dst = Tb + (size_t)trow * DIM;
    sq = tsq + trow;
  }
  float s = 0.f;
#pragma unroll
  for (int i = 0; i < 2; ++i) {
    float4 v = ((const float4*)src)[i * 64 + lane];
    s += v.x * v.x + v.y * v.y + v.z * v.z + v.w * v.w;
    ushort4 o;
    o.x = f2bf(v.x); o.y = f2bf(v.y); o.z = f2bf(v.z); o.w = f2bf(v.w);
    ((ushort4*)dst)[i * 64 + lane] = o;
  }
#pragma unroll
  for (int m = 1; m <= 32; m <<= 1) s += __shfl_xor(s, m);
  if (lane == 0) {
    *sq = s;
    if (trow >= 0) keys[trow] = 0xFFFFFFFFu;
  }
}

// =====================================================================
// Kernel 2: W [D][K] fp32 -> WbT [K][D] bf16 (transposed cast)
// =====================================================================
__global__ __launch_bounds__(256)
void prep_w_kernel(const float* __restrict__ W, unsigned short* __restrict__ WbT) {
  const int o = blockIdx.x * 256 + threadIdx.x;
  const int k = o >> 9, d = o & 511;
  WbT[o] = f2bf(W[d * KDIM + k]);
}

// =====================================================================
// Kernel 3: phi_b = logsumexp(Xb @ WbT^T) via MFMA + in-LDS logsumexp.
// =====================================================================
__global__ __launch_bounds__(256)
void phi_b_kernel(const short* __restrict__ Xb, const short* __restrict__ WbT,
                  float* __restrict__ phi_b) {
  __shared__ __align__(16) short As[BT * BKS];
  __shared__ __align__(16) short Bs[BT * BKS];
  __shared__ __align__(16) float lg[128][136];

  const int tid = threadIdx.x;
  const int wave = tid >> 6, lane = tid & 63;
  const int n0 = blockIdx.x * BT;
  const int srow = tid >> 2;
  const int sk8 = swz_slot(srow, tid & 3) * 8;
  const int wr = wave >> 1, wc = wave & 1;
  const int fr = lane & 15, g = lane >> 4;

  f32x4 acc[4][4] = {};
  for (int kt = 0; kt < DIM / BKS; ++kt) {
    const int k0 = kt * BKS;
    async_copy16(Xb + (size_t)(n0 + srow) * DIM + k0 + sk8, &As[wave * 512]);
    async_copy16(Xb + (size_t)(n0 + srow + 64) * DIM + k0 + sk8, &As[2048 + wave * 512]);
    async_copy16(WbT + (size_t)srow * DIM + k0 + sk8, &Bs[wave * 512]);
    async_copy16(WbT + (size_t)(srow + 64) * DIM + k0 + sk8, &Bs[2048 + wave * 512]);
    __syncthreads();
    short8 a[4], b[4];
#pragma unroll
    for (int i = 0; i < 4; ++i) {
      const int R = wr * 64 + i * 16 + fr;
      a[i] = *(const short8*)&As[R * BKS + swz_slot(R, g) * 8];
    }
#pragma unroll
    for (int j = 0; j < 4; ++j) {
      const int R = wc * 64 + j * 16 + fr;
      b[j] = *(const short8*)&Bs[R * BKS + swz_slot(R, g) * 8];
    }
#pragma unroll
    for (int i = 0; i < 4; ++i)
#pragma unroll
      for (int j = 0; j < 4; ++j)
        acc[i][j] = __builtin_amdgcn_mfma_f32_16x16x32_bf16(a[i], b[j], acc[i][j], 0, 0, 0);
    __syncthreads();
  }

  const int rq = g * 4;
#pragma unroll
  for (int i = 0; i < 4; ++i)
#pragma unroll
    for (int j = 0; j < 4; ++j)
#pragma unroll
      for (int q = 0; q < 4; ++q)
        lg[wr * 64 + i * 16 + rq + q][wc * 64 + j * 16 + fr] = acc[i][j][q];
  __syncthreads();

  const int row = tid >> 1, half = tid & 1;
  const float4* lr = (const float4*)(&lg[row][half * 64]);
  float mx = -3.4e38f;
#pragma unroll
  for (int c = 0; c < 16; ++c) {
    float4 v = lr[c];
    mx = fmaxf(mx, fmaxf(fmaxf(v.x, v.y), fmaxf(v.z, v.w)));
  }
  mx = fmaxf(mx, __shfl_xor(mx, 1));
  float s = 0.f;
#pragma unroll
  for (int c = 0; c < 16; ++c) {
    float4 v = lr[c];
    s += __expf(v.x - mx) + __expf(v.y - mx) + __expf(v.z - mx) + __expf(v.w - mx);
  }
  s += __shfl_xor(s, 1);
  if (half == 0) phi_b[n0 + row] = mx + logf(s);
}

// =====================================================================
// Kernel 4: fused bf16 MFMA GEMM (x @ target^T) + min_n(phi_b[n]-dot)
// 256x256 tile, BK=32, 8 waves (2Mx4N), 4 LDS buffers, 3-deep prefetch,
// 1 raw barrier / K-tile, counted vmcnt (never 0 until last tile).
// =====================================================================
__device__ __forceinline__ void stage_tile(const short* __restrict__ Xb,
                                           const short* __restrict__ Tb,
                                           short* Abuf, short* Bbuf,
                                           int n0, int m0, int k0, int tid) {
  const int row = tid >> 2;                               // 0..127
  const int sw8 = ((tid & 3) ^ ((row >> 1) & 3)) * 8;     // pre-swizzled src slot
  const int wvb = (tid >> 6) * 512;                       // wave-uniform LDS base
  async_copy16(Xb + (size_t)(n0 + row) * DIM + k0 + sw8, Abuf + wvb);
  async_copy16(Xb + (size_t)(n0 + 128 + row) * DIM + k0 + sw8, Abuf + 4096 + wvb);
  async_copy16(Tb + (size_t)(m0 + row) * DIM + k0 + sw8, Bbuf + wvb);
  async_copy16(Tb + (size_t)(m0 + 128 + row) * DIM + k0 + sw8, Bbuf + 4096 + wvb);
}

__device__ __forceinline__ void compute_tile(const short* __restrict__ Ab,
                                             const short* __restrict__ Bb,
                                             int aoff0, int boff0,
                                             f32x4 (&acc)[8][4]) {
  short8 a[8], b[4];
#pragma unroll
  for (int i = 0; i < 8; ++i) a[i] = *(const short8*)(Ab + aoff0 + i * 512);
#pragma unroll
  for (int j = 0; j < 4; ++j) b[j] = *(const short8*)(Bb + boff0 + j * 512);
  __builtin_amdgcn_s_setprio(1);
#pragma unroll
  for (int i = 0; i < 8; ++i)
#pragma unroll
    for (int j = 0; j < 4; ++j)
      acc[i][j] = __builtin_amdgcn_mfma_f32_16x16x32_bf16(a[i], b[j], acc[i][j], 0, 0, 0);
  __builtin_amdgcn_s_setprio(0);
}

__global__ __launch_bounds__(512, 2)
void gemm_min_kernel(const short* __restrict__ Xb, const short* __restrict__ Tb,
                     const float* __restrict__ phi_b, unsigned* __restrict__ keys) {
  __shared__ __align__(16) short As[4][BM * BKQ];   // 4 x 16 KB
  __shared__ __align__(16) short Bs[4][BN * BKQ];   // 4 x 16 KB  (128 KiB total)

  const int tid = threadIdx.x;
  const int wave = tid >> 6, lane = tid & 63;
  const int wm = wave >> 2, wn = wave & 3;
  const int fr = lane & 15, g = lane >> 4;
  const int n0 = blockIdx.y * BM;
  const int m0 = blockIdx.x * BN;

  // fragment read offsets (swizzle key reduces to (fr>>1)&3 for all reps)
  const int key8 = (g ^ ((fr >> 1) & 3)) * 8;
  const int aoff0 = (wm * 128 + fr) * BKQ + key8;
  const int boff0 = (wn * 64 + fr) * BKQ + key8;

  f32x4 acc[8][4] = {};

  // prologue: stage tiles 0,1,2 (12 loads/wave outstanding)
  stage_tile(Xb, Tb, As[0], Bs[0], n0, m0, 0, tid);
  stage_tile(Xb, Tb, As[1], Bs[1], n0, m0, BKQ, tid);
  stage_tile(Xb, Tb, As[2], Bs[2], n0, m0, 2 * BKQ, tid);

#pragma unroll 1
  for (int t = 0; t < 14; ++t) {
    // retire exactly tile t's 4 loads; keep tiles t+1,t+2 (8) in flight
    asm volatile("s_waitcnt vmcnt(8)" ::: "memory");
    __builtin_amdgcn_s_barrier();
    if (t < 13)
      stage_tile(Xb, Tb, As[(t + 3) & 3], Bs[(t + 3) & 3], n0, m0, (t + 3) * BKQ, tid);
    compute_tile(As[t & 3], Bs[t & 3], aoff0, boff0, acc);
  }
  // t = 14: tiles 14,15 outstanding (8) -> wait to 4 (tile 14 done)
  asm volatile("s_waitcnt vmcnt(4)" ::: "memory");
  __builtin_amdgcn_s_barrier();
  compute_tile(As[2], Bs[2], aoff0, boff0, acc);
  // t = 15: drain
  asm volatile("s_waitcnt vmcnt(0)" ::: "memory");
  __builtin_amdgcn_s_barrier();
  compute_tile(As[3], Bs[3], aoff0, boff0, acc);

  // Epilogue: v = phi_b[n] - dot(n,m); per-column min over wave's 128 rows.
  // C/D layout: col = lane&15, row = (lane>>4)*4 + q
  const int rq = g * 4;
  float mv[4] = {3.4e38f, 3.4e38f, 3.4e38f, 3.4e38f};
#pragma unroll
  for (int i = 0; i < 8; ++i) {
    float pb[4];
#pragma unroll
    for (int q = 0; q < 4; ++q) pb[q] = phi_b[n0 + wm * 128 + i * 16 + rq + q];
#pragma unroll
    for (int j = 0; j < 4; ++j)
#pragma unroll
      for (int q = 0; q < 4; ++q) mv[j] = fminf(mv[j], pb[q] - acc[i][j][q]);
  }
#pragma unroll
  for (int j = 0; j < 4; ++j) {
    float v = mv[j];
    v = fminf(v, __shfl_xor(v, 16));
    v = fminf(v, __shfl_xor(v, 32));
    if (g == 0) {
      atomicMin(&keys[m0 + wn * 64 + j * 16 + fr], fenc(v));
    }
  }
}

// =====================================================================
// Kernel 5: final reduce: mean(phi_k) + mean(phi_c). 1 block, 1024 thr.
// =====================================================================
__global__ __launch_bounds__(1024)
void finalize_kernel(const float* __restrict__ xsq, const float* __restrict__ phi_b,
                     const float* __restrict__ tsq, const unsigned* __restrict__ keys,
                     float* __restrict__ out) {
  const int t = threadIdx.x;
  double sk = 0.0, sc = 0.0;
  for (int n = t; n < N_PTS; n += 1024) sk += 0.5 * (double)xsq[n] - (double)phi_b[n];
  for (int m = t; m < M_PTS; m += 1024) sc += 0.5 * (double)tsq[m] + (double)fdec(keys[m]);
  const int lane = t & 63, wv = t >> 6;
#pragma unroll
  for (int m = 1; m <= 32; m <<= 1) {
    sk += __shfl_xor(sk, m);
    sc += __shfl_xor(sc, m);
  }
  __shared__ double pk[16], pc[16];
  if (lane == 0) { pk[wv] = sk; pc[wv] = sc; }
  __syncthreads();
  if (t == 0) {
    double a = 0.0, c = 0.0;
#pragma unroll
    for (int i = 0; i < 16; ++i) { a += pk[i]; c += pc[i]; }
    out[0] = (float)(a / N_PTS + c / M_PTS);
  }
}

// =====================================================================
extern "C" void kernel_launch(void* const* d_in, const int* in_sizes, int n_in,
                              void* d_out, int out_size, void* d_ws, size_t ws_size,
                              hipStream_t stream) {
  const float* x = (const float*)d_in[0];
  const float* tgt = (const float*)d_in[1];
  const float* W = (const float*)d_in[2];

  char* ws = (char*)d_ws;
  const size_t XB_BYTES = (size_t)N_PTS * DIM * 2;
  const size_t TB_BYTES = (size_t)M_PTS * DIM * 2;
  const size_t WT_BYTES = (size_t)KDIM * DIM * 2;
  unsigned short* Xb = (unsigned short*)ws;
  unsigned short* Tb = (unsigned short*)(ws + XB_BYTES);
  unsigned short* WbT = (unsigned short*)(ws + XB_BYTES + TB_BYTES);
  float* phi_b = (float*)(ws + XB_BYTES + TB_BYTES + WT_BYTES);
  float* xsq = phi_b + N_PTS;
  float* tsq = xsq + N_PTS;
  unsigned* keys = (unsigned*)(tsq + M_PTS);

  cast_rows_kernel<<<(N_PTS + M_PTS) / 4, 256, 0, stream>>>(x, tgt, Xb, Tb, xsq, tsq, keys);
  prep_w_kernel<<<(KDIM * DIM) / 256, 256, 0, stream>>>(W, WbT);
  phi_b_kernel<<<N_PTS / BT, 256, 0, stream>>>((const short*)Xb, (const short*)WbT, phi_b);
  gemm_min_kernel<<<dim3(M_PTS / BN, N_PTS / BM), 512, 0, stream>>>(
      (const short*)Xb, (const short*)Tb, phi_b, keys);
  finalize_kernel<<<1, 1024, 0, stream>>>(xsq, phi_b, tsq, keys, (float*)d_out);
}

// Round 4
// 105.416 us; speedup vs baseline: 1.4257x; 1.0158x over previous
//
#include <hip/hip_runtime.h>
#include <hip/hip_bf16.h>
#include <stdint.h>

typedef __attribute__((ext_vector_type(8))) short short8;
typedef __attribute__((ext_vector_type(4))) float f32x4;

#define N_PTS 8192
#define M_PTS 8192
#define DIM   512
#define KDIM  128
#define BT    128   // phi_b tile
#define BKS   32
#define BM    256   // gemm tile
#define BN    256
#define BKQ   32

// ---- float <-> order-preserving uint key (for atomicMin on float) ----
__device__ __forceinline__ unsigned fenc(float f) {
  unsigned u = __float_as_uint(f);
  return (u & 0x80000000u) ? ~u : (u | 0x80000000u);
}
__device__ __forceinline__ float fdec(unsigned k) {
  unsigned u = (k & 0x80000000u) ? (k ^ 0x80000000u) : ~k;
  return __uint_as_float(u);
}

__device__ __forceinline__ unsigned short f2bf(float f) {
  union { __hip_bfloat16 h; unsigned short u; } c;
  c.h = __float2bfloat16(f);
  return c.u;
}

// ---- async global -> LDS, 16B per lane ----
__device__ __forceinline__ void async_copy16(const void* g, void* l) {
  __builtin_amdgcn_global_load_lds(
      (const __attribute__((address_space(1))) void*)g,
      (__attribute__((address_space(3))) void*)l, 16, 0, 0);
}

// ---- LDS slot swizzle (verified: conflicts -> 0): 4 slots of 16B/row ----
__device__ __forceinline__ int swz_slot(int row, int slot) {
  return slot ^ ((row >> 1) & 3);
}

// =====================================================================
// Kernel 1: streaming cast x & target -> bf16, row sumsq, key init.
// =====================================================================
__global__ __launch_bounds__(256)
void cast_rows_kernel(const float* __restrict__ x, const float* __restrict__ tgt,
                      unsigned short* __restrict__ Xb, unsigned short* __restrict__ Tb,
                      float* __restrict__ xsq, float* __restrict__ tsq,
                      unsigned* __restrict__ keys) {
  const int gw = (blockIdx.x * 256 + threadIdx.x) >> 6;
  const int lane = threadIdx.x & 63;
  const float* src;
  unsigned short* dst;
  float* sq;
  int trow = -1;
  if (gw < N_PTS) {
    src = x + (size_t)gw * DIM;
    dst = Xb + (size_t)gw * DIM;
    sq = xsq + gw;
  } else {
    trow = gw - N_PTS;
    src = tgt + (size_t)trow * DIM;
    dst = Tb + (size_t)trow * DIM;
    sq = tsq + trow;
  }
  float s = 0.f;
#pragma unroll
  for (int i = 0; i < 2; ++i) {
    float4 v = ((const float4*)src)[i * 64 + lane];
    s += v.x * v.x + v.y * v.y + v.z * v.z + v.w * v.w;
    ushort4 o;
    o.x = f2bf(v.x); o.y = f2bf(v.y); o.z = f2bf(v.z); o.w = f2bf(v.w);
    ((ushort4*)dst)[i * 64 + lane] = o;
  }
#pragma unroll
  for (int m = 1; m <= 32; m <<= 1) s += __shfl_xor(s, m);
  if (lane == 0) {
    *sq = s;
    if (trow >= 0) keys[trow] = 0xFFFFFFFFu;
  }
}

// =====================================================================
// Kernel 2: W [D][K] fp32 -> WbT [K][D] bf16 (transposed cast)
// =====================================================================
__global__ __launch_bounds__(256)
void prep_w_kernel(const float* __restrict__ W, unsigned short* __restrict__ WbT) {
  const int o = blockIdx.x * 256 + threadIdx.x;
  const int k = o >> 9, d = o & 511;
  WbT[o] = f2bf(W[d * KDIM + k]);
}

// =====================================================================
// Kernel 3: phi_b = logsumexp(Xb @ WbT^T) via MFMA + in-LDS logsumexp.
// =====================================================================
__global__ __launch_bounds__(256)
void phi_b_kernel(const short* __restrict__ Xb, const short* __restrict__ WbT,
                  float* __restrict__ phi_b) {
  __shared__ __align__(16) short As[BT * BKS];
  __shared__ __align__(16) short Bs[BT * BKS];
  __shared__ __align__(16) float lg[128][136];

  const int tid = threadIdx.x;
  const int wave = tid >> 6, lane = tid & 63;
  const int n0 = blockIdx.x * BT;
  const int srow = tid >> 2;
  const int sk8 = swz_slot(srow, tid & 3) * 8;
  const int wr = wave >> 1, wc = wave & 1;
  const int fr = lane & 15, g = lane >> 4;

  f32x4 acc[4][4] = {};
  for (int kt = 0; kt < DIM / BKS; ++kt) {
    const int k0 = kt * BKS;
    async_copy16(Xb + (size_t)(n0 + srow) * DIM + k0 + sk8, &As[wave * 512]);
    async_copy16(Xb + (size_t)(n0 + srow + 64) * DIM + k0 + sk8, &As[2048 + wave * 512]);
    async_copy16(WbT + (size_t)srow * DIM + k0 + sk8, &Bs[wave * 512]);
    async_copy16(WbT + (size_t)(srow + 64) * DIM + k0 + sk8, &Bs[2048 + wave * 512]);
    __syncthreads();
    short8 a[4], b[4];
#pragma unroll
    for (int i = 0; i < 4; ++i) {
      const int R = wr * 64 + i * 16 + fr;
      a[i] = *(const short8*)&As[R * BKS + swz_slot(R, g) * 8];
    }
#pragma unroll
    for (int j = 0; j < 4; ++j) {
      const int R = wc * 64 + j * 16 + fr;
      b[j] = *(const short8*)&Bs[R * BKS + swz_slot(R, g) * 8];
    }
#pragma unroll
    for (int i = 0; i < 4; ++i)
#pragma unroll
      for (int j = 0; j < 4; ++j)
        acc[i][j] = __builtin_amdgcn_mfma_f32_16x16x32_bf16(a[i], b[j], acc[i][j], 0, 0, 0);
    __syncthreads();
  }

  const int rq = g * 4;
#pragma unroll
  for (int i = 0; i < 4; ++i)
#pragma unroll
    for (int j = 0; j < 4; ++j)
#pragma unroll
      for (int q = 0; q < 4; ++q)
        lg[wr * 64 + i * 16 + rq + q][wc * 64 + j * 16 + fr] = acc[i][j][q];
  __syncthreads();

  const int row = tid >> 1, half = tid & 1;
  const float4* lr = (const float4*)(&lg[row][half * 64]);
  float mx = -3.4e38f;
#pragma unroll
  for (int c = 0; c < 16; ++c) {
    float4 v = lr[c];
    mx = fmaxf(mx, fmaxf(fmaxf(v.x, v.y), fmaxf(v.z, v.w)));
  }
  mx = fmaxf(mx, __shfl_xor(mx, 1));
  float s = 0.f;
#pragma unroll
  for (int c = 0; c < 16; ++c) {
    float4 v = lr[c];
    s += __expf(v.x - mx) + __expf(v.y - mx) + __expf(v.z - mx) + __expf(v.w - mx);
  }
  s += __shfl_xor(s, 1);
  if (half == 0) phi_b[n0 + row] = mx + logf(s);
}

// =====================================================================
// Kernel 4: fused bf16 MFMA GEMM (x @ target^T) + min_n(phi_b[n]-dot)
// 256x256 tile, BK=32, 8 waves (2Mx4N), 4 LDS buffers, 3-deep prefetch.
// 2 phases/tile, each: {ds_read cluster + stage issue -> barrier ->
// lgkmcnt(0) -> setprio MFMA quadrant -> barrier}; counted vmcnt(8)
// once per tile (never 0 until the tail).
// =====================================================================
__device__ __forceinline__ void stage_A(const short* __restrict__ Xb, short* Abuf,
                                        int n0, int k0, int tid) {
  const int row = tid >> 2;
  const int sw8 = ((tid & 3) ^ ((row >> 1) & 3)) * 8;
  const int wvb = (tid >> 6) * 512;
  async_copy16(Xb + (size_t)(n0 + row) * DIM + k0 + sw8, Abuf + wvb);
  async_copy16(Xb + (size_t)(n0 + 128 + row) * DIM + k0 + sw8, Abuf + 4096 + wvb);
}
__device__ __forceinline__ void stage_B(const short* __restrict__ Tb, short* Bbuf,
                                        int m0, int k0, int tid) {
  const int row = tid >> 2;
  const int sw8 = ((tid & 3) ^ ((row >> 1) & 3)) * 8;
  const int wvb = (tid >> 6) * 512;
  async_copy16(Tb + (size_t)(m0 + row) * DIM + k0 + sw8, Bbuf + wvb);
  async_copy16(Tb + (size_t)(m0 + 128 + row) * DIM + k0 + sw8, Bbuf + 4096 + wvb);
}

template <int N> __device__ __forceinline__ void wait_vmcnt() {
  if constexpr (N == 8) asm volatile("s_waitcnt vmcnt(8)" ::: "memory");
  else if constexpr (N == 4) asm volatile("s_waitcnt vmcnt(4)" ::: "memory");
  else if constexpr (N == 0) asm volatile("s_waitcnt vmcnt(0)" ::: "memory");
}

template <bool STG, int VM>
__device__ __forceinline__ void tile_body(const short* __restrict__ Ab,
                                          const short* __restrict__ Bb,
                                          short* Anext, short* Bnext,
                                          const short* __restrict__ Xb,
                                          const short* __restrict__ Tb,
                                          int n0, int m0, int k3, int tid,
                                          int aoff0, int boff0, f32x4 (&acc)[8][4]) {
  short8 a[4], b[4];
  // ---- phase 0: reads for quadrant i=0..3 + full b, stage A(t+3) ----
#pragma unroll
  for (int i = 0; i < 4; ++i) a[i] = *(const short8*)(Ab + aoff0 + i * 512);
#pragma unroll
  for (int j = 0; j < 4; ++j) b[j] = *(const short8*)(Bb + boff0 + j * 512);
  if (STG) stage_A(Xb, Anext, n0, k3, tid);
  __builtin_amdgcn_s_barrier();
  asm volatile("s_waitcnt lgkmcnt(0)" ::: "memory");
  __builtin_amdgcn_sched_barrier(0);
  __builtin_amdgcn_s_setprio(1);
#pragma unroll
  for (int i = 0; i < 4; ++i)
#pragma unroll
    for (int j = 0; j < 4; ++j)
      acc[i][j] = __builtin_amdgcn_mfma_f32_16x16x32_bf16(a[i], b[j], acc[i][j], 0, 0, 0);
  __builtin_amdgcn_s_setprio(0);
  __builtin_amdgcn_s_barrier();
  // ---- phase 1: reads for quadrant i=4..7 (b reused), stage B(t+3) ----
  short8 a2[4];
#pragma unroll
  for (int i = 0; i < 4; ++i) a2[i] = *(const short8*)(Ab + aoff0 + (4 + i) * 512);
  if (STG) stage_B(Tb, Bnext, m0, k3, tid);
  __builtin_amdgcn_s_barrier();
  asm volatile("s_waitcnt lgkmcnt(0)" ::: "memory");
  __builtin_amdgcn_sched_barrier(0);
  __builtin_amdgcn_s_setprio(1);
#pragma unroll
  for (int i = 0; i < 4; ++i)
#pragma unroll
    for (int j = 0; j < 4; ++j)
      acc[4 + i][j] = __builtin_amdgcn_mfma_f32_16x16x32_bf16(a2[i], b[j], acc[4 + i][j], 0, 0, 0);
  __builtin_amdgcn_s_setprio(0);
  wait_vmcnt<VM>();  // retire tile t+1's 4 loads (tail: 4 / 0 / none)
  __builtin_amdgcn_s_barrier();
}

__global__ __launch_bounds__(512, 2)
void gemm_min_kernel(const short* __restrict__ Xb, const short* __restrict__ Tb,
                     const float* __restrict__ phi_b, unsigned* __restrict__ keys) {
  __shared__ __align__(16) short As[4][BM * BKQ];   // 4 x 16 KB
  __shared__ __align__(16) short Bs[4][BN * BKQ];   // 4 x 16 KB (128 KiB)

  const int tid = threadIdx.x;
  const int wave = tid >> 6, lane = tid & 63;
  const int wm = wave >> 2, wn = wave & 3;
  const int fr = lane & 15, g = lane >> 4;
  const int n0 = blockIdx.y * BM;
  const int m0 = blockIdx.x * BN;

  const int key8 = (g ^ ((fr >> 1) & 3)) * 8;
  const int aoff0 = (wm * 128 + fr) * BKQ + key8;
  const int boff0 = (wn * 64 + fr) * BKQ + key8;

  f32x4 acc[8][4] = {};

  // prologue: stage tiles 0,1,2 (12 loads/wave); retire tile 0 (vmcnt 8)
  stage_A(Xb, As[0], n0, 0, tid);        stage_B(Tb, Bs[0], m0, 0, tid);
  stage_A(Xb, As[1], n0, BKQ, tid);      stage_B(Tb, Bs[1], m0, BKQ, tid);
  stage_A(Xb, As[2], n0, 2 * BKQ, tid);  stage_B(Tb, Bs[2], m0, 2 * BKQ, tid);
  asm volatile("s_waitcnt vmcnt(8)" ::: "memory");
  __builtin_amdgcn_s_barrier();

#pragma unroll 1
  for (int t = 0; t < 13; ++t) {
    tile_body<true, 8>(As[t & 3], Bs[t & 3], As[(t + 3) & 3], Bs[(t + 3) & 3],
                       Xb, Tb, n0, m0, (t + 3) * BKQ, tid, aoff0, boff0, acc);
  }
  tile_body<false, 4>(As[1], Bs[1], As[0], Bs[0], Xb, Tb, n0, m0, 0, tid, aoff0, boff0, acc);
  tile_body<false, 0>(As[2], Bs[2], As[0], Bs[0], Xb, Tb, n0, m0, 0, tid, aoff0, boff0, acc);
  tile_body<false, -1>(As[3], Bs[3], As[0], Bs[0], Xb, Tb, n0, m0, 0, tid, aoff0, boff0, acc);

  // Epilogue: v = phi_b[n] - dot(n,m); per-column min over wave's 128 rows.
  const int rq = g * 4;
  float mv[4] = {3.4e38f, 3.4e38f, 3.4e38f, 3.4e38f};
#pragma unroll
  for (int i = 0; i < 8; ++i) {
    float pb[4];
#pragma unroll
    for (int q = 0; q < 4; ++q) pb[q] = phi_b[n0 + wm * 128 + i * 16 + rq + q];
#pragma unroll
    for (int j = 0; j < 4; ++j)
#pragma unroll
      for (int q = 0; q < 4; ++q) mv[j] = fminf(mv[j], pb[q] - acc[i][j][q]);
  }
#pragma unroll
  for (int j = 0; j < 4; ++j) {
    float v = mv[j];
    v = fminf(v, __shfl_xor(v, 16));
    v = fminf(v, __shfl_xor(v, 32));
    if (g == 0) {
      atomicMin(&keys[m0 + wn * 64 + j * 16 + fr], fenc(v));
    }
  }
}

// =====================================================================
// Kernel 5: final reduce: mean(phi_k) + mean(phi_c). 1 block, 1024 thr.
// =====================================================================
__global__ __launch_bounds__(1024)
void finalize_kernel(const float* __restrict__ xsq, const float* __restrict__ phi_b,
                     const float* __restrict__ tsq, const unsigned* __restrict__ keys,
                     float* __restrict__ out) {
  const int t = threadIdx.x;
  double sk = 0.0, sc = 0.0;
  for (int n = t; n < N_PTS; n += 1024) sk += 0.5 * (double)xsq[n] - (double)phi_b[n];
  for (int m = t; m < M_PTS; m += 1024) sc += 0.5 * (double)tsq[m] + (double)fdec(keys[m]);
  const int lane = t & 63, wv = t >> 6;
#pragma unroll
  for (int m = 1; m <= 32; m <<= 1) {
    sk += __shfl_xor(sk, m);
    sc += __shfl_xor(sc, m);
  }
  __shared__ double pk[16], pc[16];
  if (lane == 0) { pk[wv] = sk; pc[wv] = sc; }
  __syncthreads();
  if (t == 0) {
    double a = 0.0, c = 0.0;
#pragma unroll
    for (int i = 0; i < 16; ++i) { a += pk[i]; c += pc[i]; }
    out[0] = (float)(a / N_PTS + c / M_PTS);
  }
}

// =====================================================================
extern "C" void kernel_launch(void* const* d_in, const int* in_sizes, int n_in,
                              void* d_out, int out_size, void* d_ws, size_t ws_size,
                              hipStream_t stream) {
  const float* x = (const float*)d_in[0];
  const float* tgt = (const float*)d_in[1];
  const float* W = (const float*)d_in[2];

  char* ws = (char*)d_ws;
  const size_t XB_BYTES = (size_t)N_PTS * DIM * 2;
  const size_t TB_BYTES = (size_t)M_PTS * DIM * 2;
  const size_t WT_BYTES = (size_t)KDIM * DIM * 2;
  unsigned short* Xb = (unsigned short*)ws;
  unsigned short* Tb = (unsigned short*)(ws + XB_BYTES);
  unsigned short* WbT = (unsigned short*)(ws + XB_BYTES + TB_BYTES);
  float* phi_b = (float*)(ws + XB_BYTES + TB_BYTES + WT_BYTES);
  float* xsq = phi_b + N_PTS;
  float* tsq = xsq + N_PTS;
  unsigned* keys = (unsigned*)(tsq + M_PTS);

  cast_rows_kernel<<<(N_PTS + M_PTS) / 4, 256, 0, stream>>>(x, tgt, Xb, Tb, xsq, tsq, keys);
  prep_w_kernel<<<(KDIM * DIM) / 256, 256, 0, stream>>>(W, WbT);
  phi_b_kernel<<<N_PTS / BT, 256, 0, stream>>>((const short*)Xb, (const short*)WbT, phi_b);
  gemm_min_kernel<<<dim3(M_PTS / BN, N_PTS / BM), 512, 0, stream>>>(
      (const short*)Xb, (const short*)Tb, phi_b, keys);
  finalize_kernel<<<1, 1024, 0, stream>>>(xsq, phi_b, tsq, keys, (float*)d_out);
}